// Round 4
// baseline (110.333 us; speedup 1.0000x reference)
//
#include <hip/hip_runtime.h>

#define FD 128  // feature dim
#define NBKT 8
#define G1 256   // blocks for hist/place passes

typedef __attribute__((ext_vector_type(8))) short short8;   // 8 bf16
typedef __attribute__((ext_vector_type(4))) float f32x4;    // MFMA acc
typedef __attribute__((ext_vector_type(4))) unsigned int uint4e;

__device__ __forceinline__ unsigned short f2bf(float f) {
    unsigned u = __float_as_uint(f);
    u += 0x7fff + ((u >> 16) & 1);   // round-to-nearest-even
    return (unsigned short)(u >> 16);
}
__device__ __forceinline__ float bfprod(unsigned a, unsigned b) {
    float a0 = __uint_as_float(a << 16);
    float a1 = __uint_as_float(a & 0xffff0000u);
    float b0 = __uint_as_float(b << 16);
    float b1 = __uint_as_float(b & 0xffff0000u);
    return __builtin_fmaf(a0, b0, a1 * b1);
}
__device__ __forceinline__ int bkt(int d, float scale) {
    int b = (int)((float)d * scale);
    return b > (NBKT - 1) ? (NBKT - 1) : b;
}

// ---------------------------------------------------------------------------
// Kernel 0: Wt[n][k] = bf16(W[k][n])  (128x128), short8 outputs.
// ---------------------------------------------------------------------------
__global__ void wt_kernel(const float* __restrict__ W, unsigned short* __restrict__ Wt) {
    const int tid = blockIdx.x * 256 + (int)threadIdx.x;   // 0..2047
    const int n  = tid & 127;
    const int k0 = (tid >> 7) * 8;
    short8 w;
    #pragma unroll
    for (int j = 0; j < 8; ++j) w[j] = (short)f2bf(W[(k0 + j) * FD + n]);
    *(short8*)(Wt + (size_t)n * FD + k0) = w;
}

// ---------------------------------------------------------------------------
// Kernel 1: u = bf16(z @ W) via MFMA 16x16x32; fused z->bf16 writeback.
// Wt staged in LDS (32 KB, XOR-swizzled). Epilogue repacks u through LDS
// so global u-stores are coalesced 16B.
// ---------------------------------------------------------------------------
__global__ __launch_bounds__(256)
void u_mfma2(const float* __restrict__ z, const unsigned short* __restrict__ Wt,
             unsigned short* __restrict__ u, unsigned short* __restrict__ zb,
             int nrows) {
    __shared__ unsigned short Wl[FD * FD];  // 16384 ushorts = 32 KB (was the r3 bug)
    char* ldsb = (char*)Wl;
    const int tid  = (int)threadIdx.x;
    const int lane = tid & 63;
    const int wave = tid >> 6;
    const int l16  = lane & 15;
    const int kq   = lane >> 4;

    // stage Wt -> LDS, swizzled: byte = n*256 + (off16 ^ ((n&7)<<4))
    #pragma unroll
    for (int i = 0; i < 8; ++i) {
        const int c = i * 256 + tid;          // chunk 0..2047
        const int n = c >> 4;
        const int o = (c & 15) * 16;          // byte offset within row
        short8 v = *(const short8*)(Wt + (size_t)n * FD + (c & 15) * 8);
        *(short8*)(ldsb + n * 256 + (o ^ ((n & 7) << 4))) = v;
    }
    __syncthreads();

    const long rowbase = (long)blockIdx.x * 128 + wave * 32;

    f32x4 acc[2][8];
    #pragma unroll
    for (int mt = 0; mt < 2; ++mt)
        #pragma unroll
        for (int nt = 0; nt < 8; ++nt)
            acc[mt][nt] = (f32x4){0.f, 0.f, 0.f, 0.f};

    #pragma unroll
    for (int ks = 0; ks < 4; ++ks) {
        const int k0 = ks * 32 + kq * 8;

        short8 a[2];
        #pragma unroll
        for (int mt = 0; mt < 2; ++mt) {
            const long r  = rowbase + mt * 16 + l16;
            const long rc = (r < nrows) ? r : (long)(nrows - 1);
            const float4* zp = (const float4*)(z + rc * FD + k0);
            const float4 f0 = zp[0];
            const float4 f1 = zp[1];
            short8 av;
            av[0] = (short)f2bf(f0.x); av[1] = (short)f2bf(f0.y);
            av[2] = (short)f2bf(f0.z); av[3] = (short)f2bf(f0.w);
            av[4] = (short)f2bf(f1.x); av[5] = (short)f2bf(f1.y);
            av[6] = (short)f2bf(f1.z); av[7] = (short)f2bf(f1.w);
            a[mt] = av;
            if (r < nrows)
                *(short8*)(zb + r * FD + k0) = av;
        }

        short8 b[8];
        #pragma unroll
        for (int nt = 0; nt < 8; ++nt) {
            const int row = nt * 16 + l16;
            b[nt] = *(const short8*)(ldsb + row * 256 + ((ks * 64 + kq * 16) ^ ((row & 7) << 4)));
        }

        #pragma unroll
        for (int mt = 0; mt < 2; ++mt)
            #pragma unroll
            for (int nt = 0; nt < 8; ++nt)
                acc[mt][nt] = __builtin_amdgcn_mfma_f32_16x16x32_bf16(
                    a[mt], b[nt], acc[mt][nt], 0, 0, 0);
    }

    __syncthreads();   // all waves done reading Wt; reuse LDS for epilogue

    // each wave repacks its 32x128 bf16 tile in its private 8 KB quarter
    char* wb = ldsb + wave * 8192;
    #pragma unroll
    for (int mt = 0; mt < 2; ++mt)
        #pragma unroll
        for (int nt = 0; nt < 8; ++nt) {
            const f32x4 v = acc[mt][nt];
            #pragma unroll
            for (int r = 0; r < 4; ++r) {
                const int row = mt * 16 + kq * 4 + r;       // 0..31
                const int cb2 = (nt * 16 + l16) * 2;        // byte col
                *(unsigned short*)(wb + row * 256 + (cb2 ^ ((row & 7) << 4))) = f2bf(v[r]);
            }
        }
    __syncthreads();   // safe ds_write -> ds_read ordering (compiler + HW)
    #pragma unroll
    for (int i = 0; i < 8; ++i) {
        const int off = i * 1024 + lane * 16;   // 0..8191, 16B chunks
        const int row = off >> 8;
        const int inr = off & 255;
        short8 v = *(const short8*)(wb + (row << 8) + (inr ^ ((row & 7) << 4)));
        const long grow = rowbase + row;
        if (grow < nrows)
            *(short8*)(u + grow * FD + (inr >> 1)) = v;
    }
}

// ---------------------------------------------------------------------------
// Bucketing pass 1: per-block histogram of dst buckets.
// ---------------------------------------------------------------------------
__global__ __launch_bounds__(256)
void bhist(const int* __restrict__ dst, int E, int per, int* __restrict__ blockhist,
           float scale) {
    __shared__ int lh[NBKT];
    const int tid = (int)threadIdx.x;
    if (tid < NBKT) lh[tid] = 0;
    __syncthreads();
    const int e0 = blockIdx.x * per;
    const int e1 = min(E, e0 + per);
    for (int e = e0 + tid; e < e1; e += 256)
        atomicAdd(&lh[bkt(dst[e], scale)], 1);
    __syncthreads();
    if (tid < NBKT) blockhist[blockIdx.x * NBKT + tid] = lh[tid];
}

// ---------------------------------------------------------------------------
// Bucketing pass 2: scan 256 block-histograms per bucket -> per-block bases,
// plus global bucket starts[9]. Single block of 256.
// ---------------------------------------------------------------------------
__global__ __launch_bounds__(256)
void bscan(const int* __restrict__ blockhist, int* __restrict__ base,
           int* __restrict__ starts) {
    __shared__ int tmp[256];
    __shared__ int tot[NBKT];
    const int tid = (int)threadIdx.x;
    for (int bb = 0; bb < NBKT; ++bb) {
        int v = blockhist[tid * NBKT + bb];
        tmp[tid] = v;
        __syncthreads();
        for (int off = 1; off < 256; off <<= 1) {
            int t = (tid >= off) ? tmp[tid - off] : 0;
            __syncthreads();
            tmp[tid] += t;
            __syncthreads();
        }
        if (tid == 255) tot[bb] = tmp[tid];
        base[tid * NBKT + bb] = tmp[tid] - v;   // exclusive, bucket-local
        __syncthreads();
    }
    __shared__ int st[NBKT + 1];
    if (tid == 0) {
        st[0] = 0;
        for (int b = 0; b < NBKT; ++b) st[b + 1] = st[b] + tot[b];
        for (int b = 0; b <= NBKT; ++b) starts[b] = st[b];
    }
    __syncthreads();
    for (int bb = 0; bb < NBKT; ++bb)
        base[tid * NBKT + bb] += st[bb];
}

// ---------------------------------------------------------------------------
// Bucketing pass 3: deterministic rank-based placement (no global atomics).
// ---------------------------------------------------------------------------
__global__ __launch_bounds__(256)
void bplace(const int* __restrict__ dst, int E, int per, const int* __restrict__ base,
            int* __restrict__ perm, float scale) {
    __shared__ int rc[NBKT];
    __shared__ int lcnt[4][NBKT];
    __shared__ int wp[4][NBKT];
    __shared__ int cb[NBKT];
    const int tid = (int)threadIdx.x;
    const int w = tid >> 6, l = tid & 63;
    const unsigned long long ltmask = (l == 63) ? ~0ull >> 1 : ((1ull << l) - 1);
    if (tid < NBKT) rc[tid] = base[blockIdx.x * NBKT + tid];
    __syncthreads();
    const int e0 = blockIdx.x * per;
    const int e1 = min(E, e0 + per);
    for (int eb = e0; eb < e1; eb += 256) {
        const int e = eb + tid;
        const bool valid = e < e1;
        const int b = valid ? bkt(dst[e], scale) : -1;
        int rank = 0;
        #pragma unroll
        for (int bb = 0; bb < NBKT; ++bb) {
            unsigned long long m = __ballot(b == bb);
            if (b == bb) rank = __popcll(m & ltmask);
            if (l == 0) lcnt[w][bb] = __popcll(m);
        }
        __syncthreads();
        if (tid < NBKT) {
            int s = 0;
            #pragma unroll
            for (int ww = 0; ww < 4; ++ww) { wp[ww][tid] = s; s += lcnt[ww][tid]; }
            cb[tid] = rc[tid];
            rc[tid] += s;
        }
        __syncthreads();
        if (valid) perm[cb[b] + wp[w][b] + rank] = e;
        __syncthreads();
    }
}

// ---------------------------------------------------------------------------
// Edge kernel, bucketed: block handles bucket blockIdx%8 (XCD round-robin).
// zb gathers hit that XCD's L2; u gathers are non-temporal (L3-served).
// ---------------------------------------------------------------------------
__global__ __launch_bounds__(256)
void edge_bucketed(const unsigned short* __restrict__ u,
                   const unsigned short* __restrict__ zb,
                   const int* __restrict__ src, const int* __restrict__ dst,
                   const float* __restrict__ bias, const int* __restrict__ perm,
                   const int* __restrict__ starts, float* __restrict__ out) {
    const int b   = blockIdx.x & (NBKT - 1);
    const int bi  = blockIdx.x >> 3;
    const int nb  = gridDim.x >> 3;
    const int lo  = starts[b];
    const int hi  = starts[b + 1];
    const int tid = (int)threadIdx.x;
    const int slot = (tid >> 6) * 4 + ((tid & 63) >> 4);   // 0..15
    const int l16  = tid & 15;
    const float bv = bias[0];

    for (int basei = lo + bi * 16; basei < hi; basei += nb * 16) {
        const int idx = basei + slot;
        if (idx < hi) {
            const int e = perm[idx];
            const int s = src[e];
            const int t = dst[e];
            const uint4e ua = __builtin_nontemporal_load(
                (const uint4e*)(u + (size_t)s * FD) + l16);
            const uint4e za = *((const uint4e*)(zb + (size_t)t * FD) + l16);
            float sum = bfprod(ua[0], za[0]) + bfprod(ua[1], za[1])
                      + bfprod(ua[2], za[2]) + bfprod(ua[3], za[3]);
            #pragma unroll
            for (int off = 8; off >= 1; off >>= 1)
                sum += __shfl_xor(sum, off, 64);
            if (l16 == 0) out[e] = sum + bv;
        }
    }
}

// ---------------------------------------------------------------------------
// Plain (non-bucketed) edge kernel — tier-2 fallback.
// ---------------------------------------------------------------------------
__global__ __launch_bounds__(256)
void edge_kernel_bf16(const unsigned short* __restrict__ u,
                      const unsigned short* __restrict__ zb,
                      const int* __restrict__ src, const int* __restrict__ dst,
                      const float* __restrict__ bias, float* __restrict__ out,
                      int E) {
    const int gw   = (blockIdx.x * 256 + (int)threadIdx.x) >> 6;
    const int lane = (int)threadIdx.x & 63;
    const int sub  = lane >> 4;
    const int l16  = lane & 15;
    const int e    = gw * 4 + sub;
    if (e >= E) return;
    const int s = src[e];
    const int t = dst[e];
    const uint4e ua = *((const uint4e*)(u  + (size_t)s * FD) + l16);
    const uint4e za = *((const uint4e*)(zb + (size_t)t * FD) + l16);
    float sum = bfprod(ua[0], za[0]) + bfprod(ua[1], za[1])
              + bfprod(ua[2], za[2]) + bfprod(ua[3], za[3]);
    #pragma unroll
    for (int off = 8; off >= 1; off >>= 1)
        sum += __shfl_xor(sum, off, 64);
    if (l16 == 0) out[e] = sum + bias[0];
}

// ---------------------------------------------------------------------------
// Tier-3 fallback: fused per-edge bilinear, fp32 (tiny workspace).
// ---------------------------------------------------------------------------
__global__ __launch_bounds__(128)
void bilinear_fused_fallback(const float* __restrict__ z, const float* __restrict__ Wg,
                             const int* __restrict__ src, const int* __restrict__ dst,
                             const float* __restrict__ bias, float* __restrict__ out,
                             int E) {
    __shared__ float Wl[FD * FD];
    __shared__ float zs[FD];
    __shared__ float red[2];
    for (int i = threadIdx.x; i < FD * FD; i += 128) Wl[i] = Wg[i];
    __syncthreads();
    const int j = (int)threadIdx.x;
    for (int e = blockIdx.x; e < E; e += gridDim.x) {
        const int s = src[e];
        const int t = dst[e];
        zs[j] = z[(size_t)s * FD + j];
        __syncthreads();
        float acc = 0.f;
        #pragma unroll 8
        for (int d = 0; d < FD; ++d) acc += zs[d] * Wl[d * FD + j];
        float p = acc * z[(size_t)t * FD + j];
        #pragma unroll
        for (int off = 32; off >= 1; off >>= 1)
            p += __shfl_xor(p, off, 64);
        if ((j & 63) == 0) red[j >> 6] = p;
        __syncthreads();
        if (j == 0) out[e] = red[0] + red[1] + bias[0];
        __syncthreads();
    }
}

extern "C" void kernel_launch(void* const* d_in, const int* in_sizes, int n_in,
                              void* d_out, int out_size, void* d_ws, size_t ws_size,
                              hipStream_t stream) {
    const float* z    = (const float*)d_in[0];
    const int*   ei   = (const int*)d_in[1];
    const float* W    = (const float*)d_in[2];
    const float* bias = (const float*)d_in[3];
    float* out = (float*)d_out;

    const int nrows = in_sizes[0] / FD;
    const int E     = in_sizes[1] / 2;
    const int* src = ei;
    const int* dst = ei + E;

    const size_t szu = (size_t)nrows * FD * sizeof(unsigned short);  // 25.6 MB
    const size_t permb = (((size_t)E * 4) + 63) & ~(size_t)63;
    const size_t need_plain  = 2 * szu;
    const size_t need_bucket = 2 * szu + permb + (size_t)G1 * NBKT * 4 * 2 + 256;

    if (ws_size >= need_plain) {
        unsigned short* u  = (unsigned short*)d_ws;
        unsigned short* zb = (unsigned short*)((char*)d_ws + szu);
        unsigned short* Wt = (unsigned short*)d_out;   // 32 KB staging, overwritten later

        wt_kernel<<<8, 256, 0, stream>>>(W, Wt);
        const int nb1 = (nrows + 127) / 128;
        u_mfma2<<<nb1, 256, 0, stream>>>(z, Wt, u, zb, nrows);

        if (ws_size >= need_bucket) {
            int* perm      = (int*)((char*)d_ws + 2 * szu);
            int* blockhist = (int*)((char*)d_ws + 2 * szu + permb);
            int* base      = blockhist + G1 * NBKT;
            int* starts    = base + G1 * NBKT;

            const int chunks_total = (E + 255) / 256;
            const int cpb = (chunks_total + G1 - 1) / G1;
            const int per = cpb * 256;
            const float scale = (float)NBKT / (float)nrows;

            bhist<<<G1, 256, 0, stream>>>(dst, E, per, blockhist, scale);
            bscan<<<1, 256, 0, stream>>>(blockhist, base, starts);
            bplace<<<G1, 256, 0, stream>>>(dst, E, per, base, perm, scale);
            edge_bucketed<<<2048, 256, 0, stream>>>(u, zb, src, dst, bias, perm,
                                                    starts, out);
        } else {
            const int nb2 = (E + 15) / 16;
            edge_kernel_bf16<<<nb2, 256, 0, stream>>>(u, zb, src, dst, bias, out, E);
        }
    } else {
        bilinear_fused_fallback<<<2048, 128, 0, stream>>>(z, W, src, dst, bias, out, E);
    }
}

// Round 5
// 92.346 us; speedup vs baseline: 1.1948x; 1.1948x over previous
//
#include <hip/hip_runtime.h>

#define FD 128  // feature dim
#define NBKT 8
#define G1 256   // blocks for hist/place passes

typedef __attribute__((ext_vector_type(8))) short short8;   // 8 bf16
typedef __attribute__((ext_vector_type(4))) float f32x4;    // MFMA acc
typedef __attribute__((ext_vector_type(4))) unsigned int uint4e;

__device__ __forceinline__ unsigned short f2bf(float f) {
    unsigned u = __float_as_uint(f);
    u += 0x7fff + ((u >> 16) & 1);   // round-to-nearest-even
    return (unsigned short)(u >> 16);
}
__device__ __forceinline__ float bfprod(unsigned a, unsigned b) {
    float a0 = __uint_as_float(a << 16);
    float a1 = __uint_as_float(a & 0xffff0000u);
    float b0 = __uint_as_float(b << 16);
    float b1 = __uint_as_float(b & 0xffff0000u);
    return __builtin_fmaf(a0, b0, a1 * b1);
}
__device__ __forceinline__ int bkt(int d, float scale) {
    int b = (int)((float)d * scale);
    return b > (NBKT - 1) ? (NBKT - 1) : b;
}

// ---------------------------------------------------------------------------
// Kernel 0: Wt[n][k] = bf16(W[k][n])  (128x128), short8 outputs.
// ---------------------------------------------------------------------------
__global__ void wt_kernel(const float* __restrict__ W, unsigned short* __restrict__ Wt) {
    const int tid = blockIdx.x * 256 + (int)threadIdx.x;   // 0..2047
    const int n  = tid & 127;
    const int k0 = (tid >> 7) * 8;
    short8 w;
    #pragma unroll
    for (int j = 0; j < 8; ++j) w[j] = (short)f2bf(W[(k0 + j) * FD + n]);
    *(short8*)(Wt + (size_t)n * FD + k0) = w;
}

// ---------------------------------------------------------------------------
// Kernel 1: u = bf16(z @ W) via MFMA 16x16x32; fused z->bf16 writeback.
// Wt staged in LDS (32 KB, XOR-swizzled). Epilogue repacks u through LDS
// so global u-stores are coalesced 16B. (Unchanged from round 4 — verified.)
// ---------------------------------------------------------------------------
__global__ __launch_bounds__(256)
void u_mfma2(const float* __restrict__ z, const unsigned short* __restrict__ Wt,
             unsigned short* __restrict__ u, unsigned short* __restrict__ zb,
             int nrows) {
    __shared__ unsigned short Wl[FD * FD];  // 32 KB
    char* ldsb = (char*)Wl;
    const int tid  = (int)threadIdx.x;
    const int lane = tid & 63;
    const int wave = tid >> 6;
    const int l16  = lane & 15;
    const int kq   = lane >> 4;

    #pragma unroll
    for (int i = 0; i < 8; ++i) {
        const int c = i * 256 + tid;
        const int n = c >> 4;
        const int o = (c & 15) * 16;
        short8 v = *(const short8*)(Wt + (size_t)n * FD + (c & 15) * 8);
        *(short8*)(ldsb + n * 256 + (o ^ ((n & 7) << 4))) = v;
    }
    __syncthreads();

    const long rowbase = (long)blockIdx.x * 128 + wave * 32;

    f32x4 acc[2][8];
    #pragma unroll
    for (int mt = 0; mt < 2; ++mt)
        #pragma unroll
        for (int nt = 0; nt < 8; ++nt)
            acc[mt][nt] = (f32x4){0.f, 0.f, 0.f, 0.f};

    #pragma unroll
    for (int ks = 0; ks < 4; ++ks) {
        const int k0 = ks * 32 + kq * 8;

        short8 a[2];
        #pragma unroll
        for (int mt = 0; mt < 2; ++mt) {
            const long r  = rowbase + mt * 16 + l16;
            const long rc = (r < nrows) ? r : (long)(nrows - 1);
            const float4* zp = (const float4*)(z + rc * FD + k0);
            const float4 f0 = zp[0];
            const float4 f1 = zp[1];
            short8 av;
            av[0] = (short)f2bf(f0.x); av[1] = (short)f2bf(f0.y);
            av[2] = (short)f2bf(f0.z); av[3] = (short)f2bf(f0.w);
            av[4] = (short)f2bf(f1.x); av[5] = (short)f2bf(f1.y);
            av[6] = (short)f2bf(f1.z); av[7] = (short)f2bf(f1.w);
            a[mt] = av;
            if (r < nrows)
                *(short8*)(zb + r * FD + k0) = av;
        }

        short8 b[8];
        #pragma unroll
        for (int nt = 0; nt < 8; ++nt) {
            const int row = nt * 16 + l16;
            b[nt] = *(const short8*)(ldsb + row * 256 + ((ks * 64 + kq * 16) ^ ((row & 7) << 4)));
        }

        #pragma unroll
        for (int mt = 0; mt < 2; ++mt)
            #pragma unroll
            for (int nt = 0; nt < 8; ++nt)
                acc[mt][nt] = __builtin_amdgcn_mfma_f32_16x16x32_bf16(
                    a[mt], b[nt], acc[mt][nt], 0, 0, 0);
    }

    __syncthreads();

    char* wb = ldsb + wave * 8192;
    #pragma unroll
    for (int mt = 0; mt < 2; ++mt)
        #pragma unroll
        for (int nt = 0; nt < 8; ++nt) {
            const f32x4 v = acc[mt][nt];
            #pragma unroll
            for (int r = 0; r < 4; ++r) {
                const int row = mt * 16 + kq * 4 + r;
                const int cb2 = (nt * 16 + l16) * 2;
                *(unsigned short*)(wb + row * 256 + (cb2 ^ ((row & 7) << 4))) = f2bf(v[r]);
            }
        }
    __syncthreads();
    #pragma unroll
    for (int i = 0; i < 8; ++i) {
        const int off = i * 1024 + lane * 16;
        const int row = off >> 8;
        const int inr = off & 255;
        short8 v = *(const short8*)(wb + (row << 8) + (inr ^ ((row & 7) << 4)));
        const long grow = rowbase + row;
        if (grow < nrows)
            *(short8*)(u + grow * FD + (inr >> 1)) = v;
    }
}

// ---------------------------------------------------------------------------
// Bucketing pass 1: per-block histogram, ballot-based (no LDS atomics).
// ---------------------------------------------------------------------------
__global__ __launch_bounds__(256)
void bhist(const int* __restrict__ dst, int E, int per, int* __restrict__ blockhist,
           float scale) {
    __shared__ int lh[4][NBKT];
    const int tid = (int)threadIdx.x;
    const int w = tid >> 6, l = tid & 63;
    int c = 0;   // lanes 0..7 accumulate their bucket's count for this wave
    const int e0 = blockIdx.x * per;
    const int e1 = min(E, e0 + per);
    for (int eb = e0 + w * 64; eb < e1; eb += 256) {
        const int e = eb + l;
        const bool valid = e < e1;
        const int b = valid ? bkt(dst[e], scale) : -1;
        #pragma unroll
        for (int bb = 0; bb < NBKT; ++bb) {
            unsigned long long m = __ballot(b == bb);
            if (l == bb) c += __popcll(m);
        }
    }
    if (l < NBKT) lh[w][l] = c;
    __syncthreads();
    if (tid < NBKT)
        blockhist[blockIdx.x * NBKT + tid] =
            lh[0][tid] + lh[1][tid] + lh[2][tid] + lh[3][tid];
}

// ---------------------------------------------------------------------------
// Bucketing pass 2: column-wise exclusive scan over 256 block-histograms via
// wave shfl-scans (16 barriers total, not 128). Single block of 256.
// ---------------------------------------------------------------------------
__global__ __launch_bounds__(256)
void bscan(const int* __restrict__ blockhist, int* __restrict__ base,
           int* __restrict__ starts) {
    __shared__ int wsum[4][NBKT];
    __shared__ int tot[NBKT];
    __shared__ int st[NBKT + 1];
    const int tid = (int)threadIdx.x;
    const int l = tid & 63, w = tid >> 6;
    int v[NBKT], pre[NBKT];
    #pragma unroll
    for (int b = 0; b < NBKT; ++b) v[b] = blockhist[tid * NBKT + b];
    #pragma unroll
    for (int b = 0; b < NBKT; ++b) {
        int x = v[b];
        #pragma unroll
        for (int off = 1; off < 64; off <<= 1) {
            int y = __shfl_up(x, off, 64);
            if (l >= off) x += y;
        }
        pre[b] = x - v[b];               // exclusive within wave
        if (l == 63) wsum[w][b] = x;     // wave total
    }
    __syncthreads();
    if (tid < NBKT) {
        int s = 0;
        #pragma unroll
        for (int ww = 0; ww < 4; ++ww) { int t = wsum[ww][tid]; wsum[ww][tid] = s; s += t; }
        tot[tid] = s;
    }
    __syncthreads();
    if (tid == 0) {
        int s = 0;
        for (int b = 0; b < NBKT; ++b) { st[b] = s; s += tot[b]; }
        st[NBKT] = s;
        for (int b = 0; b <= NBKT; ++b) starts[b] = st[b];
    }
    __syncthreads();
    #pragma unroll
    for (int b = 0; b < NBKT; ++b)
        base[tid * NBKT + b] = st[b] + wsum[w][b] + pre[b];
}

// ---------------------------------------------------------------------------
// Bucketing pass 3: deterministic rank-based placement; writes packed
// (src, dst, e) int4 triples so the hot loop has no dependent index chain.
// ---------------------------------------------------------------------------
__global__ __launch_bounds__(256)
void bplace(const int* __restrict__ src, const int* __restrict__ dst, int E, int per,
            const int* __restrict__ base, int4* __restrict__ pk, float scale) {
    __shared__ int rc[NBKT];
    __shared__ int lcnt[4][NBKT];
    __shared__ int wp[4][NBKT];
    __shared__ int cb[NBKT];
    const int tid = (int)threadIdx.x;
    const int w = tid >> 6, l = tid & 63;
    const unsigned long long ltmask = (l == 63) ? ~0ull >> 1 : ((1ull << l) - 1);
    if (tid < NBKT) rc[tid] = base[blockIdx.x * NBKT + tid];
    __syncthreads();
    const int e0 = blockIdx.x * per;
    const int e1 = min(E, e0 + per);
    for (int eb = e0; eb < e1; eb += 256) {
        const int e = eb + tid;
        const bool valid = e < e1;
        const int d_ = valid ? dst[e] : 0;
        const int s_ = valid ? src[e] : 0;
        const int b = valid ? bkt(d_, scale) : -1;
        int rank = 0;
        #pragma unroll
        for (int bb = 0; bb < NBKT; ++bb) {
            unsigned long long m = __ballot(b == bb);
            if (b == bb) rank = __popcll(m & ltmask);
            if (l == 0) lcnt[w][bb] = __popcll(m);
        }
        __syncthreads();
        if (tid < NBKT) {
            int s = 0;
            #pragma unroll
            for (int ww = 0; ww < 4; ++ww) { wp[ww][tid] = s; s += lcnt[ww][tid]; }
            cb[tid] = rc[tid];
            rc[tid] += s;
        }
        __syncthreads();
        if (valid) {
            const int pos = cb[b] + wp[w][b] + rank;
            pk[pos] = (int4){s_, d_, e, 0};
        }
        __syncthreads();
    }
}

// ---------------------------------------------------------------------------
// Edge kernel, bucketed: block handles bucket blockIdx%8 (XCD round-robin).
// zb gathers hit the home XCD's L2; u gathers are L3-served (NO nt hint —
// round-4's nt flag evicted u from L3 and cost 127 MB HBM/replay).
// ---------------------------------------------------------------------------
__global__ __launch_bounds__(256)
void edge_bucketed2(const unsigned short* __restrict__ u,
                    const unsigned short* __restrict__ zb,
                    const float* __restrict__ bias, const int4* __restrict__ pk,
                    const int* __restrict__ starts, float* __restrict__ out) {
    const int b   = blockIdx.x & (NBKT - 1);
    const int bi  = blockIdx.x >> 3;
    const int nb  = gridDim.x >> 3;
    const int lo  = starts[b];
    const int hi  = starts[b + 1];
    const int tid = (int)threadIdx.x;
    const int slot = tid >> 4;        // 0..15 (contiguous 16-lane groups)
    const int l16  = tid & 15;
    const float bv = bias[0];

    for (int basei = lo + bi * 16; basei < hi; basei += nb * 16) {
        const int idx = basei + slot;
        if (idx < hi) {
            const int4 p = pk[idx];   // broadcast across the 16 lanes
            const uint4e ua = *((const uint4e*)(u  + (size_t)p.x * FD) + l16);
            const uint4e za = *((const uint4e*)(zb + (size_t)p.y * FD) + l16);
            float sum = bfprod(ua[0], za[0]) + bfprod(ua[1], za[1])
                      + bfprod(ua[2], za[2]) + bfprod(ua[3], za[3]);
            #pragma unroll
            for (int off = 8; off >= 1; off >>= 1)
                sum += __shfl_xor(sum, off, 64);
            if (l16 == 0) out[p.z] = sum + bv;
        }
    }
}

// ---------------------------------------------------------------------------
// Plain (non-bucketed) edge kernel — tier-2 fallback.
// ---------------------------------------------------------------------------
__global__ __launch_bounds__(256)
void edge_kernel_bf16(const unsigned short* __restrict__ u,
                      const unsigned short* __restrict__ zb,
                      const int* __restrict__ src, const int* __restrict__ dst,
                      const float* __restrict__ bias, float* __restrict__ out,
                      int E) {
    const int gw   = (blockIdx.x * 256 + (int)threadIdx.x) >> 6;
    const int lane = (int)threadIdx.x & 63;
    const int sub  = lane >> 4;
    const int l16  = lane & 15;
    const int e    = gw * 4 + sub;
    if (e >= E) return;
    const int s = src[e];
    const int t = dst[e];
    const uint4e ua = *((const uint4e*)(u  + (size_t)s * FD) + l16);
    const uint4e za = *((const uint4e*)(zb + (size_t)t * FD) + l16);
    float sum = bfprod(ua[0], za[0]) + bfprod(ua[1], za[1])
              + bfprod(ua[2], za[2]) + bfprod(ua[3], za[3]);
    #pragma unroll
    for (int off = 8; off >= 1; off >>= 1)
        sum += __shfl_xor(sum, off, 64);
    if (l16 == 0) out[e] = sum + bias[0];
}

// ---------------------------------------------------------------------------
// Tier-3 fallback: fused per-edge bilinear, fp32 (tiny workspace).
// ---------------------------------------------------------------------------
__global__ __launch_bounds__(128)
void bilinear_fused_fallback(const float* __restrict__ z, const float* __restrict__ Wg,
                             const int* __restrict__ src, const int* __restrict__ dst,
                             const float* __restrict__ bias, float* __restrict__ out,
                             int E) {
    __shared__ float Wl[FD * FD];
    __shared__ float zs[FD];
    __shared__ float red[2];
    for (int i = threadIdx.x; i < FD * FD; i += 128) Wl[i] = Wg[i];
    __syncthreads();
    const int j = (int)threadIdx.x;
    for (int e = blockIdx.x; e < E; e += gridDim.x) {
        const int s = src[e];
        const int t = dst[e];
        zs[j] = z[(size_t)s * FD + j];
        __syncthreads();
        float acc = 0.f;
        #pragma unroll 8
        for (int d = 0; d < FD; ++d) acc += zs[d] * Wl[d * FD + j];
        float p = acc * z[(size_t)t * FD + j];
        #pragma unroll
        for (int off = 32; off >= 1; off >>= 1)
            p += __shfl_xor(p, off, 64);
        if ((j & 63) == 0) red[j >> 6] = p;
        __syncthreads();
        if (j == 0) out[e] = red[0] + red[1] + bias[0];
        __syncthreads();
    }
}

extern "C" void kernel_launch(void* const* d_in, const int* in_sizes, int n_in,
                              void* d_out, int out_size, void* d_ws, size_t ws_size,
                              hipStream_t stream) {
    const float* z    = (const float*)d_in[0];
    const int*   ei   = (const int*)d_in[1];
    const float* W    = (const float*)d_in[2];
    const float* bias = (const float*)d_in[3];
    float* out = (float*)d_out;

    const int nrows = in_sizes[0] / FD;
    const int E     = in_sizes[1] / 2;
    const int* src = ei;
    const int* dst = ei + E;

    const size_t szu = (size_t)nrows * FD * sizeof(unsigned short);  // 25.6 MB
    const size_t pkb = (size_t)E * sizeof(int4);                     // 10.24 MB
    const size_t histb = (size_t)G1 * NBKT * sizeof(int);
    const size_t need_plain  = 2 * szu;
    const size_t need_bucket = 2 * szu + pkb + 2 * histb + (NBKT + 1) * sizeof(int) + 64;

    if (ws_size >= need_plain) {
        char* wsp = (char*)d_ws;
        unsigned short* u  = (unsigned short*)wsp;
        unsigned short* zb = (unsigned short*)(wsp + szu);
        unsigned short* Wt = (unsigned short*)d_out;   // 32 KB staging; edge pass
                                                       // later overwrites all of d_out

        wt_kernel<<<8, 256, 0, stream>>>(W, Wt);
        const int nb1 = (nrows + 127) / 128;
        u_mfma2<<<nb1, 256, 0, stream>>>(z, Wt, u, zb, nrows);

        if (ws_size >= need_bucket) {
            int4* pk       = (int4*)(wsp + 2 * szu);
            int* blockhist = (int*)(wsp + 2 * szu + pkb);
            int* base      = blockhist + G1 * NBKT;
            int* starts    = base + G1 * NBKT;

            const int chunks_total = (E + 255) / 256;
            const int cpb = (chunks_total + G1 - 1) / G1;
            const int per = cpb * 256;
            const float scale = (float)NBKT / (float)nrows;

            bhist<<<G1, 256, 0, stream>>>(dst, E, per, blockhist, scale);
            bscan<<<1, 256, 0, stream>>>(blockhist, base, starts);
            bplace<<<G1, 256, 0, stream>>>(src, dst, E, per, base, pk, scale);
            edge_bucketed2<<<2048, 256, 0, stream>>>(u, zb, bias, pk, starts, out);
        } else {
            const int nb2 = (E + 15) / 16;
            edge_kernel_bf16<<<nb2, 256, 0, stream>>>(u, zb, src, dst, bias, out, E);
        }
    } else {
        bilinear_fused_fallback<<<2048, 128, 0, stream>>>(z, W, src, dst, bias, out, E);
    }
}

// Round 6
// 79.217 us; speedup vs baseline: 1.3928x; 1.1657x over previous
//
#include <hip/hip_runtime.h>

#define FD 128  // feature dim

typedef __attribute__((ext_vector_type(8))) short short8;   // 8 bf16
typedef __attribute__((ext_vector_type(4))) float f32x4;    // MFMA acc

__device__ __forceinline__ unsigned short f2bf(float f) {
    unsigned u = __float_as_uint(f);
    u += 0x7fff + ((u >> 16) & 1);   // round-to-nearest-even
    return (unsigned short)(u >> 16);
}

// ---------------------------------------------------------------------------
// Kernel 0: Wt[n][k] = bf16(W[k][n])  (128x128), short8 outputs.
// ---------------------------------------------------------------------------
__global__ void wt_kernel(const float* __restrict__ W, unsigned short* __restrict__ Wt) {
    const int tid = blockIdx.x * 256 + (int)threadIdx.x;   // 0..2047
    const int n  = tid & 127;
    const int k0 = (tid >> 7) * 8;
    short8 w;
    #pragma unroll
    for (int j = 0; j < 8; ++j) w[j] = (short)f2bf(W[(k0 + j) * FD + n]);
    *(short8*)(Wt + (size_t)n * FD + k0) = w;
}

// ---------------------------------------------------------------------------
// Kernel 1: u = bf16(z @ W) via MFMA 16x16x32; fused z->bf16 writeback.
// Wt staged in LDS (32 KB, XOR-swizzled). Epilogue repacks u through LDS
// so global u-stores are coalesced 16B. (Unchanged — verified rounds 4/5.)
// ---------------------------------------------------------------------------
__global__ __launch_bounds__(256)
void u_mfma2(const float* __restrict__ z, const unsigned short* __restrict__ Wt,
             unsigned short* __restrict__ u, unsigned short* __restrict__ zb,
             int nrows) {
    __shared__ unsigned short Wl[FD * FD];  // 32 KB
    char* ldsb = (char*)Wl;
    const int tid  = (int)threadIdx.x;
    const int lane = tid & 63;
    const int wave = tid >> 6;
    const int l16  = lane & 15;
    const int kq   = lane >> 4;

    #pragma unroll
    for (int i = 0; i < 8; ++i) {
        const int c = i * 256 + tid;
        const int n = c >> 4;
        const int o = (c & 15) * 16;
        short8 v = *(const short8*)(Wt + (size_t)n * FD + (c & 15) * 8);
        *(short8*)(ldsb + n * 256 + (o ^ ((n & 7) << 4))) = v;
    }
    __syncthreads();

    const long rowbase = (long)blockIdx.x * 128 + wave * 32;

    f32x4 acc[2][8];
    #pragma unroll
    for (int mt = 0; mt < 2; ++mt)
        #pragma unroll
        for (int nt = 0; nt < 8; ++nt)
            acc[mt][nt] = (f32x4){0.f, 0.f, 0.f, 0.f};

    #pragma unroll
    for (int ks = 0; ks < 4; ++ks) {
        const int k0 = ks * 32 + kq * 8;

        short8 a[2];
        #pragma unroll
        for (int mt = 0; mt < 2; ++mt) {
            const long r  = rowbase + mt * 16 + l16;
            const long rc = (r < nrows) ? r : (long)(nrows - 1);
            const float4* zp = (const float4*)(z + rc * FD + k0);
            const float4 f0 = zp[0];
            const float4 f1 = zp[1];
            short8 av;
            av[0] = (short)f2bf(f0.x); av[1] = (short)f2bf(f0.y);
            av[2] = (short)f2bf(f0.z); av[3] = (short)f2bf(f0.w);
            av[4] = (short)f2bf(f1.x); av[5] = (short)f2bf(f1.y);
            av[6] = (short)f2bf(f1.z); av[7] = (short)f2bf(f1.w);
            a[mt] = av;
            if (r < nrows)
                *(short8*)(zb + r * FD + k0) = av;
        }

        short8 b[8];
        #pragma unroll
        for (int nt = 0; nt < 8; ++nt) {
            const int row = nt * 16 + l16;
            b[nt] = *(const short8*)(ldsb + row * 256 + ((ks * 64 + kq * 16) ^ ((row & 7) << 4)));
        }

        #pragma unroll
        for (int mt = 0; mt < 2; ++mt)
            #pragma unroll
            for (int nt = 0; nt < 8; ++nt)
                acc[mt][nt] = __builtin_amdgcn_mfma_f32_16x16x32_bf16(
                    a[mt], b[nt], acc[mt][nt], 0, 0, 0);
    }

    __syncthreads();

    char* wb = ldsb + wave * 8192;
    #pragma unroll
    for (int mt = 0; mt < 2; ++mt)
        #pragma unroll
        for (int nt = 0; nt < 8; ++nt) {
            const f32x4 v = acc[mt][nt];
            #pragma unroll
            for (int r = 0; r < 4; ++r) {
                const int row = mt * 16 + kq * 4 + r;
                const int cb2 = (nt * 16 + l16) * 2;
                *(unsigned short*)(wb + row * 256 + (cb2 ^ ((row & 7) << 4))) = f2bf(v[r]);
            }
        }
    __syncthreads();
    #pragma unroll
    for (int i = 0; i < 8; ++i) {
        const int off = i * 1024 + lane * 16;
        const int row = off >> 8;
        const int inr = off & 255;
        short8 v = *(const short8*)(wb + (row << 8) + (inr ^ ((row & 7) << 4)));
        const long grow = rowbase + row;
        if (grow < nrows)
            *(short8*)(u + grow * FD + (inr >> 1)) = v;
    }
}

// ---------------------------------------------------------------------------
// Kernel 2: MFMA edge kernel. One wave handles 16 edges:
//   A[e][k] = u[src_e][k],  B[k][e'] = zb[dst_e'][k]  (e,e' = 0..15)
//   4x mfma_f32_16x16x32_bf16 accumulate D; diagonal D[e][e] = dot products.
// Fragment mapping (same as verified u_mfma2):
//   A: lane l -> row l&15, k-quarter (l>>4)*8..+8  -> 16B load
//   B: lane l -> col l&15, k-quarter (l>>4)*8..+8  -> 16B load (same shape!)
//   D: lane l, reg r -> row (l>>4)*4+r, col l&15; diagonal e at lanes with
//      l16>>2 == kq, reg r = l16&3.
// All dot/reduce work moves to the MFMA pipe; no shuffles, ~12 VALU/16 edges.
// ---------------------------------------------------------------------------
__global__ __launch_bounds__(256)
void edge_mfma(const unsigned short* __restrict__ u,
               const unsigned short* __restrict__ zb,
               const int* __restrict__ src, const int* __restrict__ dst,
               const float* __restrict__ bias, float* __restrict__ out, int E) {
    const int tid  = (int)threadIdx.x;
    const int lane = tid & 63;
    const int l16  = lane & 15;
    const int kq   = lane >> 4;
    const long wg0 = (long)blockIdx.x * 4 + (tid >> 6);
    const long nw  = (long)gridDim.x * 4;
    const float bv = bias[0];
    const bool isdiag = (l16 >> 2) == kq;
    const int  r = l16 & 3;

    for (long g = wg0 * 16; g < E; g += nw * 16) {
        const long ei = g + l16;
        const long ec = (ei < E) ? ei : (long)(E - 1);
        const int s = src[ec];
        const int t = dst[ec];
        const short8* ub = (const short8*)(u  + (size_t)s * FD);  // 16 x 16B per row
        const short8* zB = (const short8*)(zb + (size_t)t * FD);

        f32x4 acc = (f32x4){0.f, 0.f, 0.f, 0.f};
        #pragma unroll
        for (int ks = 0; ks < 4; ++ks)
            acc = __builtin_amdgcn_mfma_f32_16x16x32_bf16(
                ub[ks * 4 + kq], zB[ks * 4 + kq], acc, 0, 0, 0);

        if (isdiag && ei < E) {
            const float v = (r == 0) ? acc[0] : (r == 1) ? acc[1]
                          : (r == 2) ? acc[2] : acc[3];
            out[ei] = v + bv;
        }
    }
}

// ---------------------------------------------------------------------------
// Fallback (workspace too small): fused per-edge bilinear, fp32.
// ---------------------------------------------------------------------------
__global__ __launch_bounds__(128)
void bilinear_fused_fallback(const float* __restrict__ z, const float* __restrict__ Wg,
                             const int* __restrict__ src, const int* __restrict__ dst,
                             const float* __restrict__ bias, float* __restrict__ out,
                             int E) {
    __shared__ float Wl[FD * FD];
    __shared__ float zs[FD];
    __shared__ float red[2];
    for (int i = threadIdx.x; i < FD * FD; i += 128) Wl[i] = Wg[i];
    __syncthreads();
    const int j = (int)threadIdx.x;
    for (int e = blockIdx.x; e < E; e += gridDim.x) {
        const int s = src[e];
        const int t = dst[e];
        zs[j] = z[(size_t)s * FD + j];
        __syncthreads();
        float acc = 0.f;
        #pragma unroll 8
        for (int d = 0; d < FD; ++d) acc += zs[d] * Wl[d * FD + j];
        float p = acc * z[(size_t)t * FD + j];
        #pragma unroll
        for (int off = 32; off >= 1; off >>= 1)
            p += __shfl_xor(p, off, 64);
        if ((j & 63) == 0) red[j >> 6] = p;
        __syncthreads();
        if (j == 0) out[e] = red[0] + red[1] + bias[0];
        __syncthreads();
    }
}

extern "C" void kernel_launch(void* const* d_in, const int* in_sizes, int n_in,
                              void* d_out, int out_size, void* d_ws, size_t ws_size,
                              hipStream_t stream) {
    const float* z    = (const float*)d_in[0];
    const int*   ei   = (const int*)d_in[1];
    const float* W    = (const float*)d_in[2];
    const float* bias = (const float*)d_in[3];
    float* out = (float*)d_out;

    const int nrows = in_sizes[0] / FD;
    const int E     = in_sizes[1] / 2;
    const int* src = ei;
    const int* dst = ei + E;

    const size_t szu = (size_t)nrows * FD * sizeof(unsigned short);  // 25.6 MB
    const size_t need = 2 * szu;   // u + zb

    if (ws_size >= need) {
        char* wsp = (char*)d_ws;
        unsigned short* u  = (unsigned short*)wsp;
        unsigned short* zb = (unsigned short*)(wsp + szu);
        unsigned short* Wt = (unsigned short*)d_out;   // 32 KB staging; edge pass
                                                       // later overwrites all of d_out

        wt_kernel<<<8, 256, 0, stream>>>(W, Wt);
        const int nb1 = (nrows + 127) / 128;
        u_mfma2<<<nb1, 256, 0, stream>>>(z, Wt, u, zb, nrows);
        edge_mfma<<<2048, 256, 0, stream>>>(u, zb, src, dst, bias, out, E);
    } else {
        bilinear_fused_fallback<<<2048, 128, 0, stream>>>(z, W, src, dst, bias, out, E);
    }
}